// Round 5
// baseline (490.328 us; speedup 1.0000x reference)
//
#include <hip/hip_runtime.h>
#include <cstdint>
#include <cstddef>

// DenseCaps dynamic routing, MI355X. B=256, R=2048, NC=10, OUT=16, IN=8, 3 iters.
//
// R5: kill the LDS bottleneck found in R4 (SQ_LDS_BANK_CONFLICT=1.07e7:
// the sacc vector-RMW and vs reads had lane-stride 16 dwords -> 5-way bank
// conflicts; LDS unit saturated, VALUBusy 34%).
//  - b-tile shrunk 16 -> 4: s-partials now live in REGISTERS (acc[4][16],
//    statically unrolled) -- the LDS s-accumulation is gone entirely.
//  - vs (vsum staging) re-laid out with row stride 20 floats: b128 reads
//    are 2-way max (free); all groups read the same address (broadcast).
//  - Flush: shuffle-reduce across the wave's 4 groups (xor16/32), then a
//    stride-11-padded 11KB LDS tile (consecutive-bank scalar writes),
//    then 2-way-spread global atomics (as R4).
//  - W[r] fragment (128 floats) stays in VGPRs; grid 2048 = 64 bgrp x 32
//    rblk; XCD = blockIdx%8 = rblk%8 so blocks sharing a W column share L2.
// Deferred logits b_k = b_in + dot(u, v0+..+v_{k-1}) as verified in R2/R4.

#define B_   256
#define R_   2048
#define NC_  10

typedef __attribute__((ext_vector_type(4))) float f32x4;

__device__ __forceinline__ float rsum16(float x){
  x += __shfl_xor(x, 1, 16);
  x += __shfl_xor(x, 2, 16);
  x += __shfl_xor(x, 4, 16);
  x += __shfl_xor(x, 8, 16);
  return x;
}
__device__ __forceinline__ float rmax16(float x){
  x = fmaxf(x, __shfl_xor(x, 1, 16));
  x = fmaxf(x, __shfl_xor(x, 2, 16));
  x = fmaxf(x, __shfl_xor(x, 4, 16));
  x = fmaxf(x, __shfl_xor(x, 8, 16));
  return x;
}

// MODE 0: c = softmax(b_in)        -> s0 += c*u
// MODE k: vsum = sum_j<k squash(s_j); c = softmax(b_in + u.vsum) -> s_k += c*u
// MODE 3 additionally writes c to c_out.
template<int MODE>
__global__ __launch_bounds__(256, 2) void route_pass(
    const float* __restrict__ x,     // [256][2048][8]
    const float* __restrict__ W,     // [2048][8][160]
    const float* __restrict__ b_in,  // [2048][10]
    float*       __restrict__ c_out, // [256][2048][10]
    const float* __restrict__ s0,    // each s: [2][256][160] (2-way spread)
    const float* __restrict__ s1,
    const float* __restrict__ s2,
    float*       __restrict__ s_out)
{
  const int t    = threadIdx.x;
  const int blkr = blockIdx.x & 31;   // r-column (XCD = blkr%8)
  const int bgrp = blockIdx.x >> 5;   // 0..63
  const int b0   = bgrp * 4;
  const int n    = t & 15;
  const int grp  = t >> 4;            // 0..15: route-within-chunk
  const int w    = t >> 6;            // wave id 0..3
  const int nn   = (n < NC_) ? n : (NC_ - 1);

  __shared__ float xs[4 * 128];       // [bq][rr][i]   2 KB
  __shared__ float vs[4 * 200];       // [bq][n*20+o]  3.2 KB (stride 20: 2-way banks)
  __shared__ float wred[4 * 704];     // [w][bq*176 + o*11 + n]  11 KB

  // ---- stage vsum = sum_j squash(s_j) for this block's 4 b's (wave w <-> bq w)
  if (MODE >= 1 && n < NC_ && (t & 63) < 16){
    const float* sl[3] = {s0, s1, s2};
    float vr[16];
    #pragma unroll
    for (int o = 0; o < 16; ++o) vr[o] = 0.f;
    #pragma unroll
    for (int j = 0; j < MODE; ++j){
      const float* sp = sl[j] + (size_t)(b0 + w) * 160 + n * 16;
      float row[16]; float ssq = 0.f;
      #pragma unroll
      for (int o = 0; o < 16; ++o){
        float v2 = sp[o] + sp[40960 + o];       // merge 2-way spread
        row[o] = v2; ssq = fmaf(v2, v2, ssq);
      }
      float f = sqrtf(ssq) / (1.f + ssq + 1e-8f);
      #pragma unroll
      for (int o = 0; o < 16; ++o) vr[o] = fmaf(f, row[o], vr[o]);
    }
    #pragma unroll
    for (int o = 0; o < 16; ++o) vs[w * 200 + n * 20 + o] = vr[o];
  }

  float acc[4][16];                   // s-partials in REGISTERS
  #pragma unroll
  for (int bq = 0; bq < 4; ++bq)
    #pragma unroll
    for (int o = 0; o < 16; ++o) acc[bq][o] = 0.f;

  for (int rc4 = 0; rc4 < 4; ++rc4){
    const int r0 = blkr * 64 + rc4 * 16;
    const int r  = r0 + grp;
    __syncthreads();                  // xs readers done (also vs visibility @0)
    // stage x tile: [4 bq][16 rr][8] = 128 uint4, coalesced 512B runs
    if (t < 128){
      int bq = t >> 5, rr = (t >> 1) & 15, hf = t & 1;
      *(uint4*)(xs + bq * 128 + rr * 8 + hf * 4) =
        *(const uint4*)(x + ((size_t)(b0 + bq) * R_ + r0 + rr) * 8 + hf * 4);
    }
    __syncthreads();

    // W[r] fragment for this lane's class -> 32 float4 in VGPRs
    f32x4 w4[32];
    {
      const float* wp = W + (size_t)r * 1280 + nn * 16;
      #pragma unroll
      for (int i = 0; i < 8; ++i)
        #pragma unroll
        for (int q = 0; q < 4; ++q)
          w4[i * 4 + q] = *(const f32x4*)(wp + i * 160 + q * 4);
    }
    const float binr = b_in[r * NC_ + nn];
    float c0r = 0.f;
    if (MODE == 0){
      float bnew = (n < NC_) ? binr : -1e30f;
      float m = rmax16(bnew);
      float e = __expf(bnew - m);
      float sum = rsum16(e);
      c0r = e / sum;
    }

    #pragma unroll
    for (int bi = 0; bi < 4; ++bi){   // static unroll: acc[bi] stays in regs
      const f32x4* xp = (const f32x4*)(xs + bi * 128 + grp * 8);
      f32x4 xa = xp[0], xb = xp[1];   // broadcast within group
      float xr[8] = {xa[0], xa[1], xa[2], xa[3], xb[0], xb[1], xb[2], xb[3]};
      float u[16];
      #pragma unroll
      for (int o = 0; o < 16; ++o) u[o] = 0.f;
      #pragma unroll
      for (int i = 0; i < 8; ++i)
        #pragma unroll
        for (int o = 0; o < 16; ++o)
          u[o] = fmaf(xr[i], w4[i * 4 + (o >> 2)][o & 3], u[o]);

      float c;
      if (MODE == 0){
        c = c0r;
      } else {
        const f32x4* vp = (const f32x4*)(vs + bi * 200 + nn * 20);
        f32x4 v0 = vp[0], v1 = vp[1], v2 = vp[2], v3 = vp[3];
        float t0 = 0.f, t1 = 0.f, t2 = 0.f, t3 = 0.f;
        #pragma unroll
        for (int j = 0; j < 4; ++j){
          t0 = fmaf(u[j],      v0[j], t0);
          t1 = fmaf(u[4 + j],  v1[j], t1);
          t2 = fmaf(u[8 + j],  v2[j], t2);
          t3 = fmaf(u[12 + j], v3[j], t3);
        }
        float td = (t0 + t1) + (t2 + t3);
        float bnew = (n < NC_) ? (binr + td) : -1e30f;
        float m = rmax16(bnew);
        float e = __expf(bnew - m);    // n>=10 -> e=0 -> c=0
        float sum = rsum16(e);
        c = e / sum;
        if (MODE == 3 && n < NC_)
          c_out[((size_t)(b0 + bi) * R_ + r) * NC_ + n] = c;
      }
      // register accumulation (c=0 for n>=10 -> harmless zeros)
      #pragma unroll
      for (int o = 0; o < 16; ++o) acc[bi][o] = fmaf(c, u[o], acc[bi][o]);
    }
  }

  // ---- flush: shuffle-reduce across the wave's 4 groups, stage per-wave
  // partials in stride-11-padded LDS, block-reduce, spread atomics.
  #pragma unroll
  for (int bq = 0; bq < 4; ++bq)
    #pragma unroll
    for (int o = 0; o < 16; ++o){
      float a = acc[bq][o];
      a += __shfl_xor(a, 16);
      a += __shfl_xor(a, 32);
      acc[bq][o] = a;
    }
  __syncthreads();                    // xs readers done before wred reuse? (separate arrays; barrier for visibility)
  if ((t & 63) < 16 && n < NC_){
    #pragma unroll
    for (int bq = 0; bq < 4; ++bq)
      #pragma unroll
      for (int o = 0; o < 16; ++o)
        wred[w * 704 + bq * 176 + o * 11 + n] = acc[bq][o];
  }
  __syncthreads();
  for (int idx = t; idx < 640; idx += 256){
    int bq  = idx / 160;
    int rem = idx - bq * 160;
    int o   = rem / 10;
    int n2  = rem - o * 10;
    float tot = 0.f;
    #pragma unroll
    for (int ww = 0; ww < 4; ++ww)
      tot += wred[ww * 704 + bq * 176 + o * 11 + n2];
    atomicAdd(s_out + (blockIdx.x & 1) * 40960 +
              (size_t)(b0 + bq) * 160 + n2 * 16 + o, tot);
  }
}

// ---------- final squash: v_out = squash(s3) (merging 2-way spread) ----------
__global__ __launch_bounds__(256) void squash_final(const float* __restrict__ s,
                                                    float* __restrict__ vout){
  int g = blockIdx.x * 256 + threadIdx.x;   // 16 lanes per (b,n) row
  float xv = s[g] + s[40960 + g];
  float ss = rsum16(xv * xv);
  float norm = sqrtf(ss);
  vout[g] = (norm / (1.f + ss + 1e-8f)) * xv;
}

extern "C" void kernel_launch(void* const* d_in, const int* in_sizes, int n_in,
                              void* d_out, int out_size, void* d_ws, size_t ws_size,
                              hipStream_t stream){
  const float* x    = (const float*)d_in[0];   // [256,2048,8]
  const float* W    = (const float*)d_in[1];   // [2048,8,160]
  const float* b_in = (const float*)d_in[2];   // [2048,10]
  float* out = (float*)d_out;
  float* out_v = out;                 // 40960 floats
  float* c_out = out + 40960;         // [B][R][NC] final coupling coeffs

  float* s0 = (float*)d_ws;           // 4 buffers x 2 spread-halves x 160KB
  float* s1 = s0 + 2 * 40960;
  float* s2 = s1 + 2 * 40960;
  float* s3 = s2 + 2 * 40960;

  hipMemsetAsync(s0, 0, 8 * 40960 * sizeof(float), stream);
  route_pass<0><<<2048, 256, 0, stream>>>(x, W, b_in, c_out, s0, s1, s2, s0);
  route_pass<1><<<2048, 256, 0, stream>>>(x, W, b_in, c_out, s0, s1, s2, s1);
  route_pass<2><<<2048, 256, 0, stream>>>(x, W, b_in, c_out, s0, s1, s2, s2);
  route_pass<3><<<2048, 256, 0, stream>>>(x, W, b_in, c_out, s0, s1, s2, s3);
  squash_final<<<160, 256, 0, stream>>>(s3, out_v);
}